// Round 1
// baseline (1144.743 us; speedup 1.0000x reference)
//
#include <hip/hip_runtime.h>
#include <hip/hip_bf16.h>

typedef unsigned int u32;
typedef unsigned long long u64;

// ---------------- workspace layout (bytes) ----------------
#define OFF_Y      0ull            // 512*4096*4 = 8,388,608
#define OFF_SCORES 8388608ull      // 36864*4    = 147,456
#define OFF_DRAW   8536064ull      // 36*4096*4  = 589,824
#define OFF_HIST   9125888ull      // 131072*4   = 524,288
#define OFF_SEL    9650176ull      // 256
#define OFF_CNT    9650432ull      // 256
#define OFF_CAND   9650688ull      // 8192*8     = 65,536
#define MEMSET_LEN (524288ull + 256ull + 256ull + 65536ull)   // hist..cand
#define OFF_TOPV   9716224ull      // 6000*4 -> 24,576
#define OFF_TOPI   9740800ull      // 24,576
#define OFF_BOXES  9765376ull      // 6000*16 -> 96,256
#define OFF_VW     9861632ull      // 96*8 -> 1,024
#define OFF_MASK   9862656ull      // 6000*96*8 = 4,608,000
#define OFF_KEEP   14470656ull     // 2,048
#define OFF_KC     14472704ull     // 256
#define OFF_KW     14472960ull     // 1,024

#define NS     36864
#define PRE    6000
#define POST   300
#define SORTN  8192
#define MROW   96   // mask words per row (94 used)

// ================= K1: 3x3 conv 512->512 + bias + relu =================
// block: 256 thr = 64 cols x 4 groups; block tile: 32 co x 4 rows x 64 cols
// grid: 16 co-blocks x 16 h-blocks = 256
__global__ __launch_bounds__(256) void k_conv1(const float* __restrict__ x,
                                               const float* __restrict__ gw,
                                               const float* __restrict__ gb,
                                               float* __restrict__ y) {
    __shared__ float xs[16 * 6 * 66];                 // 25,344 B
    __shared__ __align__(16) float wsm[16 * 9 * 32];  // 18,432 B
    const int t = threadIdx.x;
    const int tx = t & 63;
    const int tg = t >> 6;
    const int cob = (blockIdx.x & 15) << 5;
    const int h0 = (blockIdx.x >> 4) << 2;
    const int co_off = tg << 3;

    float acc[8][4];
#pragma unroll
    for (int c = 0; c < 8; ++c)
#pragma unroll
        for (int r = 0; r < 4; ++r) acc[c][r] = 0.f;

    for (int cc = 0; cc < 32; ++cc) {
        const int cib = cc * 16;
        for (int idx = t; idx < 16 * 6 * 66; idx += 256) {
            int ci = idx / 396;
            int rem = idx - ci * 396;
            int row = rem / 66;
            int col = rem - row * 66;
            int gr = h0 + row - 1, gc = col - 1;
            float v = 0.f;
            if ((unsigned)gr < 64u && (unsigned)gc < 64u)
                v = x[(cib + ci) * 4096 + gr * 64 + gc];
            xs[idx] = v;
        }
        for (int idx = t; idx < 16 * 9 * 32; idx += 256) {
            int co = idx / 144;
            int rem = idx - co * 144;
            int ci = rem / 9;
            int k = rem - ci * 9;
            wsm[(ci * 9 + k) * 32 + co] = gw[(cob + co) * 4608 + (cib + ci) * 9 + k];
        }
        __syncthreads();

        for (int ci = 0; ci < 16; ++ci) {
            const float* xb = xs + ci * 396 + tx;
            const float* wb = wsm + ci * 288 + co_off;
            float xr[6][3];
#pragma unroll
            for (int rr = 0; rr < 6; ++rr)
#pragma unroll
                for (int c3 = 0; c3 < 3; ++c3) xr[rr][c3] = xb[rr * 66 + c3];
#pragma unroll
            for (int k = 0; k < 9; ++k) {
                const int kh = k / 3, kw = k - kh * 3;
                float4 wa = *(const float4*)(wb + k * 32);
                float4 wc = *(const float4*)(wb + k * 32 + 4);
#pragma unroll
                for (int r = 0; r < 4; ++r) {
                    float xv = xr[r + kh][kw];
                    acc[0][r] += wa.x * xv; acc[1][r] += wa.y * xv;
                    acc[2][r] += wa.z * xv; acc[3][r] += wa.w * xv;
                    acc[4][r] += wc.x * xv; acc[5][r] += wc.y * xv;
                    acc[6][r] += wc.z * xv; acc[7][r] += wc.w * xv;
                }
            }
        }
        __syncthreads();
    }
#pragma unroll
    for (int c = 0; c < 8; ++c) {
        float bias = gb[cob + co_off + c];
#pragma unroll
        for (int r = 0; r < 4; ++r) {
            float v = acc[c][r] + bias;
            v = v > 0.f ? v : 0.f;
            y[(cob + co_off + c) * 4096 + (h0 + r) * 64 + tx] = v;
        }
    }
}

// ================= K2: 1x1 heads + sigmoid + histogram =================
// block 256 = 64 px x 4 groups; grid 64 (px chunks)
__global__ __launch_bounds__(256) void k_heads(const float* __restrict__ y,
                                               const float* __restrict__ cw,
                                               const float* __restrict__ cb,
                                               const float* __restrict__ bw,
                                               const float* __restrict__ bb,
                                               float* __restrict__ scores,
                                               float* __restrict__ draw,
                                               u32* __restrict__ hist) {
    __shared__ float ys[128 * 64];  // 32 KB
    const int t = threadIdx.x;
    const int px = t & 63;
    const int gu = __builtin_amdgcn_readfirstlane(t >> 6);
    const int px0 = blockIdx.x << 6;
    const int nch = (gu == 0) ? 12 : 11;

    const float* wrow[12];
#pragma unroll
    for (int j = 0; j < 12; ++j) {
        int ch = gu + 4 * j;
        if (ch < 9) wrow[j] = cw + ch * 512;
        else if (ch < 45) wrow[j] = bw + (ch - 9) * 512;
        else wrow[j] = cw;  // unused
    }
    float acc[12];
#pragma unroll
    for (int j = 0; j < 12; ++j) acc[j] = 0.f;

    for (int ccq = 0; ccq < 4; ++ccq) {
        const int cib = ccq << 7;
        for (int idx = t; idx < 128 * 64; idx += 256) {
            int ci = idx >> 6;
            int p = idx & 63;
            ys[idx] = y[(cib + ci) * 4096 + px0 + p];
        }
        __syncthreads();
        for (int ci = 0; ci < 128; ++ci) {
            float v = ys[ci * 64 + px];
            int cig = cib + ci;
#pragma unroll
            for (int j = 0; j < 12; ++j)
                if (j < nch) acc[j] += v * wrow[j][cig];
        }
        __syncthreads();
    }
    for (int j = 0; j < nch; ++j) {
        int ch = gu + 4 * j;
        int sp = px0 + px;
        float z = acc[j] + ((ch < 9) ? cb[ch] : bb[ch - 9]);
        if (ch < 9) {
            float s = 1.f / (1.f + expf(-z));
            int i = ch * 4096 + sp;
            scores[i] = s;
            u32 sb = __float_as_uint(s);
            atomicAdd(&hist[sb >> 13], 1u);
        } else {
            draw[(ch - 9) * 4096 + sp] = z;
        }
    }
}

// ================= K3: find boundary bin (rank 6000 from top) =================
__global__ __launch_bounds__(1024) void k_scan_hist(const u32* __restrict__ hist,
                                                    int* __restrict__ sel) {
    __shared__ u32 csum[1024];
    int t = threadIdx.x;
    u32 s = 0;
    const u32* hp = hist + t * 128;
    for (int i = 0; i < 128; ++i) s += hp[i];
    csum[t] = s;
    __syncthreads();
    if (t == 0) {
        u32 run = 0;
        int chunk = 1023;
        for (; chunk >= 0; --chunk) {
            u32 c = csum[chunk];
            if (run + c >= (u32)PRE) break;
            run += c;
        }
        if (chunk < 0) { sel[0] = 0; return; }
        int bstar = chunk * 128;
        for (int b = chunk * 128 + 127; b >= chunk * 128; --b) {
            u32 c = hist[b];
            if (run + c >= (u32)PRE) { bstar = b; break; }
            run += c;
        }
        sel[0] = bstar;
    }
}

// ================= K4: compact candidates (bin >= bstar) =================
__global__ __launch_bounds__(256) void k_compact(const float* __restrict__ scores,
                                                 const int* __restrict__ sel,
                                                 u64* __restrict__ cand,
                                                 int* __restrict__ cnt) {
    int i = blockIdx.x * 256 + threadIdx.x;
    if (i >= NS) return;
    u32 sb = __float_as_uint(scores[i]);
    if ((int)(sb >> 13) >= sel[0]) {
        int pos = atomicAdd(cnt, 1);
        if (pos < SORTN) cand[pos] = ((u64)sb << 32) | (u32)(~i);
    }
}

// ================= K5: bitonic sort 8192 keys (descending) =================
__global__ __launch_bounds__(1024) void k_sort(const u64* __restrict__ cand,
                                               float* __restrict__ topv,
                                               int* __restrict__ topi) {
    __shared__ u64 sk[SORTN];  // 64 KB
    int t = threadIdx.x;
    for (int i = t; i < SORTN; i += 1024) sk[i] = cand[i];
    __syncthreads();
    for (int k = 2; k <= SORTN; k <<= 1) {
        for (int j = k >> 1; j > 0; j >>= 1) {
            for (int i = t; i < SORTN; i += 1024) {
                int l = i ^ j;
                if (l > i) {
                    u64 a = sk[i], b = sk[l];
                    bool up = (i & k) == 0;
                    if (up ? (a < b) : (a > b)) { sk[i] = b; sk[l] = a; }
                }
            }
            __syncthreads();
        }
    }
    for (int r = t; r < PRE; r += 1024) {
        u64 key = sk[r];
        topv[r] = __uint_as_float((u32)(key >> 32));
        topi[r] = (int)(~(u32)key);
    }
}

// ================= K6: decode + clip + valid bitmask =================
__global__ __launch_bounds__(256) void k_decode(const float* __restrict__ draw,
                                                const float* __restrict__ anchors,
                                                const int* __restrict__ ishape,
                                                const int* __restrict__ topi,
                                                float* __restrict__ boxes,
                                                u64* __restrict__ vw) {
    int r = blockIdx.x * 256 + threadIdx.x;
    bool valid = false;
    if (r < PRE) {
        int i = topi[r];
        int c = i >> 10;
        int t4 = i & 1023;
        int base = c * 4096 + (t4 << 2);
        float dx = draw[base], dy = draw[base + 1];
        float dw = draw[base + 2], dh = draw[base + 3];
        const float* a = anchors + i * 4;
        float aw = a[2] - a[0], ah = a[3] - a[1];
        float ax = a[0] + 0.5f * aw, ay = a[1] + 0.5f * ah;
        const float CLIPV = (float)4.135166556742356;
        dw = fminf(dw, CLIPV);
        dh = fminf(dh, CLIPV);
        float px = dx * aw + ax, py = dy * ah + ay;
        float pw = expf(dw) * aw, ph = expf(dh) * ah;
        float wimg = (float)ishape[1], himg = (float)ishape[0];
        float x1 = fminf(fmaxf(px - 0.5f * pw, 0.f), wimg);
        float y1 = fminf(fmaxf(py - 0.5f * ph, 0.f), himg);
        float x2 = fminf(fmaxf(px + 0.5f * pw, 0.f), wimg);
        float y2 = fminf(fmaxf(py + 0.5f * ph, 0.f), himg);
        valid = (x2 - x1 >= 16.f) && (y2 - y1 >= 16.f);
        *(float4*)(boxes + r * 4) = make_float4(x1, y1, x2, y2);
    }
    u64 bm = __ballot(valid);
    if ((threadIdx.x & 63) == 0) vw[r >> 6] = bm;
}

// ================= K7: suppression bitmask (iou > 0.7, j > row) =================
// block 256: 16 rows x 16 words-per-chunk; 6 column chunks of 1024
__global__ __launch_bounds__(256) void k_mask(const float* __restrict__ boxes,
                                              u64* __restrict__ mask) {
    __shared__ float4 cbx[16 * 65];  // stride 65 to break bank conflicts
    const int t = threadIdx.x;
    const int r0 = blockIdx.x << 4;
    const int row = r0 + (t >> 4);
    const int wloc = t & 15;
    float4 rb = *(const float4*)(boxes + row * 4);
    float area_a = (rb.z - rb.x) * (rb.w - rb.y);
    for (int chunk = 0; chunk < 6; ++chunk) {
        int j0c = chunk << 10;
        for (int idx = t; idx < 1024; idx += 256) {
            int j = j0c + idx;
            float4 v = make_float4(0.f, 0.f, 0.f, 0.f);
            if (j < PRE) v = *(const float4*)(boxes + j * 4);
            cbx[(idx >> 6) * 65 + (idx & 63)] = v;
        }
        __syncthreads();
        u64 bits = 0;
        const float4* cbr = cbx + wloc * 65;
        for (int b = 0; b < 64; ++b) {
            int j = j0c + (wloc << 6) + b;
            float4 ob = cbr[b];
            float area_b = (ob.z - ob.x) * (ob.w - ob.y);
            float ltx = fmaxf(rb.x, ob.x), lty = fmaxf(rb.y, ob.y);
            float rbx = fminf(rb.z, ob.z), rby = fminf(rb.w, ob.w);
            float wx = fmaxf(rbx - ltx, 0.f), wy = fmaxf(rby - lty, 0.f);
            float inter = wx * wy;
            float uni = area_a + area_b - inter;
            float iou = (uni > 0.f) ? (inter / uni) : 0.f;
            if (iou > 0.7f && j > row && j < PRE) bits |= (1ull << b);
        }
        mask[(size_t)row * MROW + (chunk << 4) + wloc] = bits;
        __syncthreads();
    }
}

// ================= K8: serial greedy NMS scan (single wave), early-stop @300 ===
__global__ __launch_bounds__(64) void k_nms(const u64* __restrict__ mask,
                                            const u64* __restrict__ vw,
                                            int* __restrict__ keeplist,
                                            int* __restrict__ kc_out,
                                            u64* __restrict__ kw_out) {
    __shared__ u64 rem[MROW];
    const int lane = threadIdx.x;
    for (int q = lane; q < MROW; q += 64) rem[q] = 0ull;
    __syncthreads();
    int kc = 0;
    bool done = false;
    for (int w = 0; w < 94 && !done; ++w) {
        u64 aw = vw[w] & ~rem[w];
        u64 kwbits = 0;
        while (aw) {
            int b = __builtin_ctzll(aw);
            int r = (w << 6) + b;
            if (lane == 0) keeplist[kc] = r;
            kc++;
            kwbits |= (1ull << b);
            if (kc >= POST) { done = true; break; }
            const u64* rowm = mask + (size_t)r * MROW;
            u64 rw = rowm[w];
            rem[lane] |= rowm[lane];
            if (lane < 30) rem[64 + lane] |= rowm[64 + lane];
            aw &= ~(1ull << b);
            aw &= ~rw;
        }
        if (lane == 0) kw_out[w] = kwbits;
        __syncthreads();
    }
    if (lane == 0) *kc_out = kc;
}

// ================= K9: write 300 boxes + scores =================
__global__ __launch_bounds__(384) void k_out(const float* __restrict__ boxes,
                                             const float* __restrict__ topv,
                                             const int* __restrict__ keeplist,
                                             const int* __restrict__ kc_p,
                                             const u64* __restrict__ kw,
                                             float* __restrict__ out) {
    int j = threadIdx.x;
    if (j >= POST) return;
    int kc = *kc_p;
    int r;
    float sc;
    if (j < kc) {
        r = keeplist[j];
        sc = topv[r];
    } else {
        int target = j - kc;
        r = PRE - 1;
        int cum = 0;
        for (int w = 0; w < 94; ++w) {
            u64 kb = kw[w];
            int nvalid = (w < 93) ? 64 : 48;
            u64 vmask = (nvalid == 64) ? ~0ull : ((1ull << nvalid) - 1ull);
            u64 nk = (~kb) & vmask;
            int c = __popcll(nk);
            if (cum + c > target) {
                int need = target - cum;
                u64 m = nk;
                for (int q = 0; q < need; ++q) m &= (m - 1);
                r = (w << 6) + __builtin_ctzll(m);
                break;
            }
            cum += c;
        }
        sc = -1.0f;
    }
    out[j * 4 + 0] = boxes[r * 4 + 0];
    out[j * 4 + 1] = boxes[r * 4 + 1];
    out[j * 4 + 2] = boxes[r * 4 + 2];
    out[j * 4 + 3] = boxes[r * 4 + 3];
    out[1200 + j] = sc;
}

extern "C" void kernel_launch(void* const* d_in, const int* in_sizes, int n_in,
                              void* d_out, int out_size, void* d_ws, size_t ws_size,
                              hipStream_t stream) {
    const float* x = (const float*)d_in[0];
    const float* anchors = (const float*)d_in[1];
    const int* ishape = (const int*)d_in[2];
    const float* c1w = (const float*)d_in[3];
    const float* c1b = (const float*)d_in[4];
    const float* clw = (const float*)d_in[5];
    const float* clb = (const float*)d_in[6];
    const float* bxw = (const float*)d_in[7];
    const float* bxb = (const float*)d_in[8];

    char* ws = (char*)d_ws;
    float* y      = (float*)(ws + OFF_Y);
    float* scores = (float*)(ws + OFF_SCORES);
    float* draw   = (float*)(ws + OFF_DRAW);
    u32*   hist   = (u32*)(ws + OFF_HIST);
    int*   sel    = (int*)(ws + OFF_SEL);
    int*   cnt    = (int*)(ws + OFF_CNT);
    u64*   cand   = (u64*)(ws + OFF_CAND);
    float* topv   = (float*)(ws + OFF_TOPV);
    int*   topi   = (int*)(ws + OFF_TOPI);
    float* boxes  = (float*)(ws + OFF_BOXES);
    u64*   vw     = (u64*)(ws + OFF_VW);
    u64*   mask   = (u64*)(ws + OFF_MASK);
    int*   keepl  = (int*)(ws + OFF_KEEP);
    int*   kc     = (int*)(ws + OFF_KC);
    u64*   kw     = (u64*)(ws + OFF_KW);

    hipMemsetAsync(ws + OFF_HIST, 0, MEMSET_LEN, stream);

    k_conv1<<<256, 256, 0, stream>>>(x, c1w, c1b, y);
    k_heads<<<64, 256, 0, stream>>>(y, clw, clb, bxw, bxb, scores, draw, hist);
    k_scan_hist<<<1, 1024, 0, stream>>>(hist, sel);
    k_compact<<<(NS + 255) / 256, 256, 0, stream>>>(scores, sel, cand, cnt);
    k_sort<<<1, 1024, 0, stream>>>(cand, topv, topi);
    k_decode<<<24, 256, 0, stream>>>(draw, anchors, ishape, topi, boxes, vw);
    k_mask<<<PRE / 16, 256, 0, stream>>>(boxes, mask);
    k_nms<<<1, 64, 0, stream>>>(mask, vw, keepl, kc, kw);
    k_out<<<1, 384, 0, stream>>>(boxes, topv, keepl, kc, kw, (float*)d_out);
}

// Round 2
// 1053.600 us; speedup vs baseline: 1.0865x; 1.0865x over previous
//
#include <hip/hip_runtime.h>
#include <hip/hip_bf16.h>

typedef unsigned int u32;
typedef unsigned long long u64;

// ---------------- workspace layout (bytes) ----------------
#define OFF_Y      0ull            // 512*4096*4 = 8,388,608
#define OFF_SCORES 8388608ull      // 36864*4    = 147,456
#define OFF_DRAW   8536064ull      // 36*4096*4  = 589,824
#define OFF_HIST   9125888ull      // 131072*4   = 524,288
#define OFF_SEL    9650176ull      // 256
#define OFF_CNT    9650432ull      // 256
#define OFF_CAND   9650688ull      // 8192*8     = 65,536
#define MEMSET_LEN (524288ull + 256ull + 256ull + 65536ull)   // hist..cand
#define OFF_TOPV   9716224ull      // 6000*4 -> 24,576
#define OFF_TOPI   9740800ull      // 24,576
#define OFF_BOXES  9765376ull      // 6000*16 -> 96,256
#define OFF_VW     9861632ull      // 96*8 -> 1,024
#define OFF_MASK   9862656ull      // 6000*96*8 = 4,608,000
#define OFF_KEEP   14470656ull     // 2,048
#define OFF_KC     14472704ull     // 256
#define OFF_KW     14472960ull     // 1,024

#define NS     36864
#define PRE    6000
#define POST   300
#define SORTN  8192
#define MROW   96   // mask words per row (94 used)

// ================= K1: 3x3 conv 512->512 + bias + relu =================
// Redesign: weights via wave-uniform scalar loads (s_load, SGPR operands to
// v_fmac) -> zero DS-pipe traffic for weights. 2-row tiles -> grid 512 ->
// 2 blocks/CU (8 waves/CU). LDS holds only x halo tiles (16.9 KB).
// block: 256 thr = 64 cols x 4 waves; tile: 32 co x 2 rows x 64 cols
// grid: 16 co-blocks x 32 h-blocks = 512
__global__ __launch_bounds__(256) void k_conv1(const float* __restrict__ x,
                                               const float* __restrict__ gw,
                                               const float* __restrict__ gb,
                                               float* __restrict__ y) {
    __shared__ float xs[16 * 4 * 66];  // 16 ci x 4 rows x 66 cols = 16,896 B
    const int t = threadIdx.x;
    const int tx = t & 63;
    const int tg = __builtin_amdgcn_readfirstlane(t >> 6);  // wave id, uniform
    const int cob = (blockIdx.x & 15) << 5;
    const int h0 = (blockIdx.x >> 4) << 1;
    const int co_base = cob + (tg << 3);

    float acc[8][2];
#pragma unroll
    for (int c = 0; c < 8; ++c) {
        acc[c][0] = 0.f;
        acc[c][1] = 0.f;
    }

    for (int cc = 0; cc < 32; ++cc) {
        const int cib = cc << 4;
        // stage x tile: rows h0-1 .. h0+2, cols -1 .. 64 (zero-padded halo)
        for (int idx = t; idx < 16 * 4 * 66; idx += 256) {
            int ci = idx / 264;
            int rem = idx - ci * 264;
            int row = rem / 66;
            int col = rem - row * 66;
            int gr = h0 + row - 1, gc = col - 1;
            float v = 0.f;
            if ((unsigned)gr < 64u && (unsigned)gc < 64u)
                v = x[(cib + ci) * 4096 + (gr << 6) + gc];
            xs[idx] = v;
        }
        __syncthreads();

        const float* wbase = gw + (size_t)co_base * 4608 + cib * 9;
        for (int ci = 0; ci < 16; ++ci) {
            const float* xb = xs + ci * 264 + tx;
            float xr[4][3];
#pragma unroll
            for (int rr = 0; rr < 4; ++rr)
#pragma unroll
                for (int c3 = 0; c3 < 3; ++c3) xr[rr][c3] = xb[rr * 66 + c3];
#pragma unroll
            for (int co = 0; co < 8; ++co) {
                const float* wp = wbase + co * 4608 + ci * 9;  // uniform -> s_load
                float wk[9];
#pragma unroll
                for (int k = 0; k < 9; ++k) wk[k] = wp[k];
#pragma unroll
                for (int k = 0; k < 9; ++k) {
                    const int kh = k / 3, kw = k - kh * 3;
                    acc[co][0] += wk[k] * xr[kh][kw];
                    acc[co][1] += wk[k] * xr[kh + 1][kw];
                }
            }
        }
        __syncthreads();
    }
#pragma unroll
    for (int co = 0; co < 8; ++co) {
        float bias = gb[co_base + co];
#pragma unroll
        for (int r = 0; r < 2; ++r) {
            float v = acc[co][r] + bias;
            v = v > 0.f ? v : 0.f;
            y[(co_base + co) * 4096 + ((h0 + r) << 6) + tx] = v;
        }
    }
}

// ================= K2: 1x1 heads + sigmoid + histogram =================
// block 256 = 64 px x 4 groups; grid 64 (px chunks)
__global__ __launch_bounds__(256) void k_heads(const float* __restrict__ y,
                                               const float* __restrict__ cw,
                                               const float* __restrict__ cb,
                                               const float* __restrict__ bw,
                                               const float* __restrict__ bb,
                                               float* __restrict__ scores,
                                               float* __restrict__ draw,
                                               u32* __restrict__ hist) {
    __shared__ float ys[128 * 64];  // 32 KB
    const int t = threadIdx.x;
    const int px = t & 63;
    const int gu = __builtin_amdgcn_readfirstlane(t >> 6);
    const int px0 = blockIdx.x << 6;
    const int nch = (gu == 0) ? 12 : 11;

    const float* wrow[12];
#pragma unroll
    for (int j = 0; j < 12; ++j) {
        int ch = gu + 4 * j;
        if (ch < 9) wrow[j] = cw + ch * 512;
        else if (ch < 45) wrow[j] = bw + (ch - 9) * 512;
        else wrow[j] = cw;  // unused
    }
    float acc[12];
#pragma unroll
    for (int j = 0; j < 12; ++j) acc[j] = 0.f;

    for (int ccq = 0; ccq < 4; ++ccq) {
        const int cib = ccq << 7;
        for (int idx = t; idx < 128 * 64; idx += 256) {
            int ci = idx >> 6;
            int p = idx & 63;
            ys[idx] = y[(cib + ci) * 4096 + px0 + p];
        }
        __syncthreads();
        for (int ci = 0; ci < 128; ++ci) {
            float v = ys[ci * 64 + px];
            int cig = cib + ci;
#pragma unroll
            for (int j = 0; j < 12; ++j)
                if (j < nch) acc[j] += v * wrow[j][cig];
        }
        __syncthreads();
    }
    for (int j = 0; j < nch; ++j) {
        int ch = gu + 4 * j;
        int sp = px0 + px;
        float z = acc[j] + ((ch < 9) ? cb[ch] : bb[ch - 9]);
        if (ch < 9) {
            float s = 1.f / (1.f + expf(-z));
            int i = ch * 4096 + sp;
            scores[i] = s;
            u32 sb = __float_as_uint(s);
            atomicAdd(&hist[sb >> 13], 1u);
        } else {
            draw[(ch - 9) * 4096 + sp] = z;
        }
    }
}

// ================= K3: find boundary bin (rank 6000 from top) =================
__global__ __launch_bounds__(1024) void k_scan_hist(const u32* __restrict__ hist,
                                                    int* __restrict__ sel) {
    __shared__ u32 csum[1024];
    int t = threadIdx.x;
    u32 s = 0;
    const u32* hp = hist + t * 128;
    for (int i = 0; i < 128; ++i) s += hp[i];
    csum[t] = s;
    __syncthreads();
    if (t == 0) {
        u32 run = 0;
        int chunk = 1023;
        for (; chunk >= 0; --chunk) {
            u32 c = csum[chunk];
            if (run + c >= (u32)PRE) break;
            run += c;
        }
        if (chunk < 0) { sel[0] = 0; return; }
        int bstar = chunk * 128;
        for (int b = chunk * 128 + 127; b >= chunk * 128; --b) {
            u32 c = hist[b];
            if (run + c >= (u32)PRE) { bstar = b; break; }
            run += c;
        }
        sel[0] = bstar;
    }
}

// ================= K4: compact candidates (bin >= bstar) =================
__global__ __launch_bounds__(256) void k_compact(const float* __restrict__ scores,
                                                 const int* __restrict__ sel,
                                                 u64* __restrict__ cand,
                                                 int* __restrict__ cnt) {
    int i = blockIdx.x * 256 + threadIdx.x;
    if (i >= NS) return;
    u32 sb = __float_as_uint(scores[i]);
    if ((int)(sb >> 13) >= sel[0]) {
        int pos = atomicAdd(cnt, 1);
        if (pos < SORTN) cand[pos] = ((u64)sb << 32) | (u32)(~i);
    }
}

// ================= K5: bitonic sort 8192 keys (descending) =================
__global__ __launch_bounds__(1024) void k_sort(const u64* __restrict__ cand,
                                               float* __restrict__ topv,
                                               int* __restrict__ topi) {
    __shared__ u64 sk[SORTN];  // 64 KB
    int t = threadIdx.x;
    for (int i = t; i < SORTN; i += 1024) sk[i] = cand[i];
    __syncthreads();
    for (int k = 2; k <= SORTN; k <<= 1) {
        for (int j = k >> 1; j > 0; j >>= 1) {
            for (int i = t; i < SORTN; i += 1024) {
                int l = i ^ j;
                if (l > i) {
                    u64 a = sk[i], b = sk[l];
                    bool up = (i & k) == 0;
                    if (up ? (a < b) : (a > b)) { sk[i] = b; sk[l] = a; }
                }
            }
            __syncthreads();
        }
    }
    for (int r = t; r < PRE; r += 1024) {
        u64 key = sk[r];
        topv[r] = __uint_as_float((u32)(key >> 32));
        topi[r] = (int)(~(u32)key);
    }
}

// ================= K6: decode + clip + valid bitmask =================
__global__ __launch_bounds__(256) void k_decode(const float* __restrict__ draw,
                                                const float* __restrict__ anchors,
                                                const int* __restrict__ ishape,
                                                const int* __restrict__ topi,
                                                float* __restrict__ boxes,
                                                u64* __restrict__ vw) {
    int r = blockIdx.x * 256 + threadIdx.x;
    bool valid = false;
    if (r < PRE) {
        int i = topi[r];
        int c = i >> 10;
        int t4 = i & 1023;
        int base = c * 4096 + (t4 << 2);
        float dx = draw[base], dy = draw[base + 1];
        float dw = draw[base + 2], dh = draw[base + 3];
        const float* a = anchors + i * 4;
        float aw = a[2] - a[0], ah = a[3] - a[1];
        float ax = a[0] + 0.5f * aw, ay = a[1] + 0.5f * ah;
        const float CLIPV = (float)4.135166556742356;
        dw = fminf(dw, CLIPV);
        dh = fminf(dh, CLIPV);
        float px = dx * aw + ax, py = dy * ah + ay;
        float pw = expf(dw) * aw, ph = expf(dh) * ah;
        float wimg = (float)ishape[1], himg = (float)ishape[0];
        float x1 = fminf(fmaxf(px - 0.5f * pw, 0.f), wimg);
        float y1 = fminf(fmaxf(py - 0.5f * ph, 0.f), himg);
        float x2 = fminf(fmaxf(px + 0.5f * pw, 0.f), wimg);
        float y2 = fminf(fmaxf(py + 0.5f * ph, 0.f), himg);
        valid = (x2 - x1 >= 16.f) && (y2 - y1 >= 16.f);
        *(float4*)(boxes + r * 4) = make_float4(x1, y1, x2, y2);
    }
    u64 bm = __ballot(valid);
    if ((threadIdx.x & 63) == 0) vw[r >> 6] = bm;
}

// ================= K7: suppression bitmask (iou > 0.7, j > row) =================
// block 256: 16 rows x 16 words-per-chunk; 6 column chunks of 1024
__global__ __launch_bounds__(256) void k_mask(const float* __restrict__ boxes,
                                              u64* __restrict__ mask) {
    __shared__ float4 cbx[16 * 65];  // stride 65 to break bank conflicts
    const int t = threadIdx.x;
    const int r0 = blockIdx.x << 4;
    const int row = r0 + (t >> 4);
    const int wloc = t & 15;
    float4 rb = *(const float4*)(boxes + row * 4);
    float area_a = (rb.z - rb.x) * (rb.w - rb.y);
    for (int chunk = 0; chunk < 6; ++chunk) {
        int j0c = chunk << 10;
        for (int idx = t; idx < 1024; idx += 256) {
            int j = j0c + idx;
            float4 v = make_float4(0.f, 0.f, 0.f, 0.f);
            if (j < PRE) v = *(const float4*)(boxes + j * 4);
            cbx[(idx >> 6) * 65 + (idx & 63)] = v;
        }
        __syncthreads();
        u64 bits = 0;
        const float4* cbr = cbx + wloc * 65;
        for (int b = 0; b < 64; ++b) {
            int j = j0c + (wloc << 6) + b;
            float4 ob = cbr[b];
            float area_b = (ob.z - ob.x) * (ob.w - ob.y);
            float ltx = fmaxf(rb.x, ob.x), lty = fmaxf(rb.y, ob.y);
            float rbx = fminf(rb.z, ob.z), rby = fminf(rb.w, ob.w);
            float wx = fmaxf(rbx - ltx, 0.f), wy = fmaxf(rby - lty, 0.f);
            float inter = wx * wy;
            float uni = area_a + area_b - inter;
            float iou = (uni > 0.f) ? (inter / uni) : 0.f;
            if (iou > 0.7f && j > row && j < PRE) bits |= (1ull << b);
        }
        mask[(size_t)row * MROW + (chunk << 4) + wloc] = bits;
        __syncthreads();
    }
}

// ================= K8: serial greedy NMS scan (single wave), early-stop @300 ===
__global__ __launch_bounds__(64) void k_nms(const u64* __restrict__ mask,
                                            const u64* __restrict__ vw,
                                            int* __restrict__ keeplist,
                                            int* __restrict__ kc_out,
                                            u64* __restrict__ kw_out) {
    __shared__ u64 rem[MROW];
    const int lane = threadIdx.x;
    for (int q = lane; q < MROW; q += 64) rem[q] = 0ull;
    __syncthreads();
    int kc = 0;
    bool done = false;
    for (int w = 0; w < 94 && !done; ++w) {
        u64 aw = vw[w] & ~rem[w];
        u64 kwbits = 0;
        while (aw) {
            int b = __builtin_ctzll(aw);
            int r = (w << 6) + b;
            if (lane == 0) keeplist[kc] = r;
            kc++;
            kwbits |= (1ull << b);
            if (kc >= POST) { done = true; break; }
            const u64* rowm = mask + (size_t)r * MROW;
            u64 rw = rowm[w];
            rem[lane] |= rowm[lane];
            if (lane < 30) rem[64 + lane] |= rowm[64 + lane];
            aw &= ~(1ull << b);
            aw &= ~rw;
        }
        if (lane == 0) kw_out[w] = kwbits;
        __syncthreads();
    }
    if (lane == 0) *kc_out = kc;
}

// ================= K9: write 300 boxes + scores =================
__global__ __launch_bounds__(384) void k_out(const float* __restrict__ boxes,
                                             const float* __restrict__ topv,
                                             const int* __restrict__ keeplist,
                                             const int* __restrict__ kc_p,
                                             const u64* __restrict__ kw,
                                             float* __restrict__ out) {
    int j = threadIdx.x;
    if (j >= POST) return;
    int kc = *kc_p;
    int r;
    float sc;
    if (j < kc) {
        r = keeplist[j];
        sc = topv[r];
    } else {
        int target = j - kc;
        r = PRE - 1;
        int cum = 0;
        for (int w = 0; w < 94; ++w) {
            u64 kb = kw[w];
            int nvalid = (w < 93) ? 64 : 48;
            u64 vmask = (nvalid == 64) ? ~0ull : ((1ull << nvalid) - 1ull);
            u64 nk = (~kb) & vmask;
            int c = __popcll(nk);
            if (cum + c > target) {
                int need = target - cum;
                u64 m = nk;
                for (int q = 0; q < need; ++q) m &= (m - 1);
                r = (w << 6) + __builtin_ctzll(m);
                break;
            }
            cum += c;
        }
        sc = -1.0f;
    }
    out[j * 4 + 0] = boxes[r * 4 + 0];
    out[j * 4 + 1] = boxes[r * 4 + 1];
    out[j * 4 + 2] = boxes[r * 4 + 2];
    out[j * 4 + 3] = boxes[r * 4 + 3];
    out[1200 + j] = sc;
}

extern "C" void kernel_launch(void* const* d_in, const int* in_sizes, int n_in,
                              void* d_out, int out_size, void* d_ws, size_t ws_size,
                              hipStream_t stream) {
    const float* x = (const float*)d_in[0];
    const float* anchors = (const float*)d_in[1];
    const int* ishape = (const int*)d_in[2];
    const float* c1w = (const float*)d_in[3];
    const float* c1b = (const float*)d_in[4];
    const float* clw = (const float*)d_in[5];
    const float* clb = (const float*)d_in[6];
    const float* bxw = (const float*)d_in[7];
    const float* bxb = (const float*)d_in[8];

    char* ws = (char*)d_ws;
    float* y      = (float*)(ws + OFF_Y);
    float* scores = (float*)(ws + OFF_SCORES);
    float* draw   = (float*)(ws + OFF_DRAW);
    u32*   hist   = (u32*)(ws + OFF_HIST);
    int*   sel    = (int*)(ws + OFF_SEL);
    int*   cnt    = (int*)(ws + OFF_CNT);
    u64*   cand   = (u64*)(ws + OFF_CAND);
    float* topv   = (float*)(ws + OFF_TOPV);
    int*   topi   = (int*)(ws + OFF_TOPI);
    float* boxes  = (float*)(ws + OFF_BOXES);
    u64*   vw     = (u64*)(ws + OFF_VW);
    u64*   mask   = (u64*)(ws + OFF_MASK);
    int*   keepl  = (int*)(ws + OFF_KEEP);
    int*   kc     = (int*)(ws + OFF_KC);
    u64*   kw     = (u64*)(ws + OFF_KW);

    hipMemsetAsync(ws + OFF_HIST, 0, MEMSET_LEN, stream);

    k_conv1<<<512, 256, 0, stream>>>(x, c1w, c1b, y);
    k_heads<<<64, 256, 0, stream>>>(y, clw, clb, bxw, bxb, scores, draw, hist);
    k_scan_hist<<<1, 1024, 0, stream>>>(hist, sel);
    k_compact<<<(NS + 255) / 256, 256, 0, stream>>>(scores, sel, cand, cnt);
    k_sort<<<1, 1024, 0, stream>>>(cand, topv, topi);
    k_decode<<<24, 256, 0, stream>>>(draw, anchors, ishape, topi, boxes, vw);
    k_mask<<<PRE / 16, 256, 0, stream>>>(boxes, mask);
    k_nms<<<1, 64, 0, stream>>>(mask, vw, keepl, kc, kw);
    k_out<<<1, 384, 0, stream>>>(boxes, topv, keepl, kc, kw, (float*)d_out);
}